// Round 9
// baseline (670.180 us; speedup 1.0000x reference)
//
#include <hip/hip_runtime.h>
#include <hip/hip_fp16.h>

// LSTM B=256,T=512,IN=64,H=128,L=2 + FC.
//  K0 cvt  : w_ih0 -> fp16 (tiny)
//  KG      : xg0 = x(f32).Wih0^T + bias -> [B*T][unit][4g] f16 (fused cvt)
//  KF      : both recurrent layers (L1 lags CH=8) + chunked xg1 GEMM + FC
//
// R9: phase-staggered KF. R8 measured MFMA pipe 1242 cyc + VALU 1060 cyc
// per SIMD-step running back-to-back (MfmaUtil 47 + VALUBusy 42 = 89%,
// near-zero overlap): each wave's activation depends on the MFMAs it just
// issued. Fix: split each step into two phases pairing one recurrence's
// MFMA burst with the OTHER recurrence's activation (inputs one phase old):
//   Phase A: MFMA-L0(s) [reads h0(s-1)] || act-L1(prev) -> write h1; barrier
//   Phase B: MFMA-L1    [reads h1]      || act-L0(s)    -> write h0; barrier
// MFMA pipe and VALU pipe now overlap within each phase; act results are a
// full phase old so MFMA latency is hidden. L1's act trails its MFMA by one
// iteration -> one peeled act in the epilogue emits h1(T-1). k=0 runs L1 on
// zeroed xg1t/h1 (exact zero-dynamics: gates=0 -> c,h stay 0); k=NCH runs
// L0 on bounded garbage (unconsumed). h1buf single-buffered (write->bar->
// read). Else identical to R8 (CH=8 chunked xg-phase, stale-acc trick,
// ~200-reg demand under the unified 256 ceiling).

#define TT 512
#define CH 8
#define NCH 64            // TT / CH
#define MM (256 * 512)
#define HP 136            // padded h0tile row stride

typedef _Float16 f16x4 __attribute__((ext_vector_type(4)));
typedef _Float16 f16x8 __attribute__((ext_vector_type(8)));
typedef float f32x4 __attribute__((ext_vector_type(4)));

__device__ __forceinline__ float tanh_f(float x) {
    float e = __expf(2.0f * x);
    return 1.0f - 2.0f * __builtin_amdgcn_rcpf(e + 1.0f);
}
__device__ __forceinline__ float sigm_f(float x) {
    return __builtin_amdgcn_rcpf(1.0f + __expf(-x));
}
__device__ __forceinline__ f16x8 cvt8(float4 a, float4 b) {
    f16x8 f;
    f[0] = (_Float16)a.x; f[1] = (_Float16)a.y;
    f[2] = (_Float16)a.z; f[3] = (_Float16)a.w;
    f[4] = (_Float16)b.x; f[5] = (_Float16)b.y;
    f[6] = (_Float16)b.z; f[7] = (_Float16)b.w;
    return f;
}

// ---------------- K0: fp32 -> fp16 cvt (vector4) ----------------
__global__ void cvt_f32_f16(const float* __restrict__ src,
                            _Float16* __restrict__ dst, int n4) {
    int i = blockIdx.x * blockDim.x + threadIdx.x;
    int stride = gridDim.x * blockDim.x;
    for (; i < n4; i += stride) {
        float4 v = ((const float4*)src)[i];
        f16x4 a;
        a[0] = (_Float16)v.x; a[1] = (_Float16)v.y;
        a[2] = (_Float16)v.z; a[3] = (_Float16)v.w;
        ((f16x4*)dst)[i] = a;
    }
}

// ------- KG: xg[M][u][4g] = A32[M,64] . W[512,64]^T + (bih+bhh) ----------
__global__ __launch_bounds__(256, 1) void gemm_xg0(
    const float* __restrict__ A32, const _Float16* __restrict__ W,
    const float* __restrict__ bih, const float* __restrict__ bhh,
    _Float16* __restrict__ out)
{
    const int l  = threadIdx.x & 63;
    const int w  = threadIdx.x >> 6;
    const int mb = blockIdx.x * 64 + w * 16;
    const int c  = l & 15;
    const int q  = l >> 4;

    __shared__ float biasl[512];
    for (int i = threadIdx.x; i < 512; i += 256) biasl[i] = bih[i] + bhh[i];
    __syncthreads();

    f32x4 C[32];
    #pragma unroll
    for (int i = 0; i < 32; ++i) C[i] = (f32x4){0.f, 0.f, 0.f, 0.f};

    #pragma unroll
    for (int ks = 0; ks < 2; ++ks) {
        const float* ap = A32 + (size_t)(mb + c) * 64 + ks * 32 + q * 8;
        f16x8 Af = cvt8(((const float4*)ap)[0], ((const float4*)ap)[1]);
        #pragma unroll
        for (int nt = 0; nt < 32; ++nt) {
            f16x8 Bf = *(const f16x8*)(W + (size_t)(nt * 16 + c) * 64 + ks * 32 + q * 8);
            C[nt] = __builtin_amdgcn_mfma_f32_16x16x32_f16(Af, Bf, C[nt], 0, 0, 0);
        }
    }
    #pragma unroll
    for (int uu = 0; uu < 8; ++uu) {
        float b0 = biasl[uu * 16 + c];
        float b1 = biasl[128 + uu * 16 + c];
        float b2 = biasl[256 + uu * 16 + c];
        float b3 = biasl[384 + uu * 16 + c];
        #pragma unroll
        for (int i = 0; i < 4; ++i) {
            int row = mb + q * 4 + i;
            f16x4 pk;
            pk[0] = (_Float16)(C[uu][i]      + b0);
            pk[1] = (_Float16)(C[8 + uu][i]  + b1);
            pk[2] = (_Float16)(C[16 + uu][i] + b2);
            pk[3] = (_Float16)(C[24 + uu][i] + b3);
            ((f16x4*)out)[(size_t)row * 128 + uu * 16 + c] = pk;
        }
    }
}

// ---------------- KF: phase-staggered two-layer recurrence ----------------
__global__
__attribute__((amdgpu_flat_work_group_size(512, 512), amdgpu_waves_per_eu(2, 2)))
void lstm_fused(
    const float* __restrict__ whh0, const float* __restrict__ wih1,
    const float* __restrict__ whh1,
    const float* __restrict__ bih1, const float* __restrict__ bhh1,
    const _Float16* __restrict__ xg0,   // [B*T][unit][4g] fp16 (bias incl.)
    const float* __restrict__ fc_w, const float* __restrict__ fc_b,
    float* __restrict__ out)
{
    const int t = threadIdx.x;
    const int b = blockIdx.x;
    const int w = t >> 6;
    const int l = t & 63;
    const int q = l >> 4;            // quad 0..3
    const int c = l & 15;
    const int unit = (w << 4) + c;   // 0..127

    __shared__ __align__(16) _Float16 w1lds[512 * 128];   // 128 KB
    __shared__ __align__(16) _Float16 xg1t[CH * 512];     //   8 KB
    __shared__ __align__(16) _Float16 h0tile[CH * HP];    // 2176 B
    __shared__ __align__(16) _Float16 h1buf[128];         //  256 B
    __shared__ float redbuf[128];                         //  512 B

    // ---- stage Wih1 -> LDS (one row/thread, cvt + chunk-XOR swizzle) ----
    {
        const int r = t;
        const float* src = wih1 + (size_t)r * 128;
        #pragma unroll
        for (int j = 0; j < 16; ++j)
            *(f16x8*)&w1lds[r * 128 + ((j ^ (r & 7)) << 3)] =
                cvt8(((const float4*)src)[2 * j], ((const float4*)src)[2 * j + 1]);
    }

    // ---- resident B-frags: Whh0/Whh1 rows g*128+unit, k = kt*32+q*8 ----
    f16x8 B0[4][4], B1[4][4];
    #pragma unroll
    for (int g = 0; g < 4; ++g) {
        #pragma unroll
        for (int kt = 0; kt < 4; ++kt) {
            const size_t off = (size_t)((g << 7) + unit) * 128 + (kt << 5) + (q << 3);
            B0[g][kt] = cvt8(((const float4*)(whh0 + off))[0],
                             ((const float4*)(whh0 + off))[1]);
            B1[g][kt] = cvt8(((const float4*)(whh1 + off))[0],
                             ((const float4*)(whh1 + off))[1]);
        }
    }
    float bias1g[4];
    #pragma unroll
    for (int g = 0; g < 4; ++g)
        bias1g[g] = bih1[(g << 7) + unit] + bhh1[(g << 7) + unit];

    // zeros: xg1t (k=0 L1 zero-dynamics), h1buf, h0 ring slot CH-1.
    {
        int i = t;                                   // CH*512/8 = 512 f4 slots
        ((float4*)xg1t)[i] = make_float4(0.f, 0.f, 0.f, 0.f);
    }
    if (t < 128) {
        h1buf[t] = (_Float16)0.f;
        h0tile[(CH - 1) * HP + t] = (_Float16)0.f;
    }

    // xg0 rotating prefetch regs (depth 2, compile-time indexed).
    const f16x4* __restrict__ xgp = (const f16x4*)xg0 + (size_t)b * TT * 128 + unit;
    f16x4 xr[4];
    xr[0] = xgp[0];
    xr[1] = xgp[128];
    xr[2] = xr[0]; xr[3] = xr[0];   // overwritten before first use

    // persistent accumulators; only [0] ever read (stale-lane trick).
    f32x4 a0[4], a1[4];
    #pragma unroll
    for (int g = 0; g < 4; ++g) {
        a0[g] = (f32x4){0.f, 0.f, 0.f, 0.f};
        a1[g] = (f32x4){0.f, 0.f, 0.f, 0.f};
    }
    float cst0 = 0.f, cst1 = 0.f;
    __syncthreads();

    #pragma unroll 1
    for (int k = 0; k <= NCH; ++k) {
        #pragma unroll
        for (int j = 0; j < CH; ++j) {
            const int rp = (j + CH - 1) & (CH - 1);

            // ================= Phase A =================
            // MFMA-L0(s=k*CH+j): reads h0(s-1); init C-in from xg0.
            f16x4 xv = xr[j & 3];
            #pragma unroll
            for (int g = 0; g < 4; ++g) a0[g][0] = (float)xv[g];
            #pragma unroll
            for (int kt = 0; kt < 4; ++kt) {
                f16x8 Af0 = *(const f16x8*)&h0tile[rp * HP + (kt << 5) + (q << 3)];
                #pragma unroll
                for (int g = 0; g < 4; ++g)
                    a0[g] = __builtin_amdgcn_mfma_f32_16x16x32_f16(Af0, B0[g][kt], a0[g], 0, 0, 0);
            }
            // act-L1(prev): a1 results are one full phase old -> no stall.
            {
                float gi = sigm_f(a1[0][0]);
                float gf = sigm_f(a1[1][0]);
                float gg = tanh_f(a1[2][0]);
                float go = sigm_f(a1[3][0]);
                cst1 = gf * cst1 + gi * gg;
                float hh = go * tanh_f(cst1);
                if (l < 16) h1buf[unit] = (_Float16)hh;
            }
            // xg0 prefetch for step s+2 (OOB at tail lands in ws slack)
            xr[(j + 2) & 3] = xgp[(size_t)(k * CH + j + 2) * 128];
            __syncthreads();   // B1: h1 visible

            // ================= Phase B =================
            // MFMA-L1(u=(k-1)*CH+j): reads just-written h1; C-in from xg1t.
            f16x4 x1v = *(const f16x4*)&xg1t[(j << 9) + (unit << 2)];
            #pragma unroll
            for (int g = 0; g < 4; ++g) a1[g][0] = (float)x1v[g];
            #pragma unroll
            for (int kt = 0; kt < 4; ++kt) {
                f16x8 Af1 = *(const f16x8*)&h1buf[(kt << 5) + (q << 3)];
                #pragma unroll
                for (int g = 0; g < 4; ++g)
                    a1[g] = __builtin_amdgcn_mfma_f32_16x16x32_f16(Af1, B1[g][kt], a1[g], 0, 0, 0);
            }
            // act-L0(s): a0 results are one full phase old -> no stall.
            {
                float gi = sigm_f(a0[0][0]);
                float gf = sigm_f(a0[1][0]);
                float gg = tanh_f(a0[2][0]);
                float go = sigm_f(a0[3][0]);
                cst0 = gf * cst0 + gi * gg;
                float hh = go * tanh_f(cst0);
                if (l < 16) h0tile[j * HP + unit] = (_Float16)hh;
            }
            __syncthreads();   // B2: h0 visible
        }

        // ---- xg-phase: xg1t = h0tile(chunk k) @ Wih1^T + b1 ----
        if (k < NCH) {
            f32x4 G[4];
            #pragma unroll
            for (int g = 0; g < 4; ++g)
                G[g] = (f32x4){bias1g[g], bias1g[g], bias1g[g], bias1g[g]};
            #pragma unroll
            for (int kt = 0; kt < 4; ++kt) {
                f16x8 Ah = *(const f16x8*)&h0tile[(c & 7) * HP + (kt << 5) + (q << 3)];
                #pragma unroll
                for (int g = 0; g < 4; ++g) {
                    f16x8 Bg = *(const f16x8*)&w1lds[(((g << 7) + unit) << 7) +
                                   ((((kt << 2) + q) ^ (c & 7)) << 3)];
                    G[g] = __builtin_amdgcn_mfma_f32_16x16x32_f16(Ah, Bg, G[g], 0, 0, 0);
                }
            }
            #pragma unroll
            for (int i2 = 0; i2 < 4; ++i2) {   // D rows 8..15 dup rows 0..7
                f16x4 pk;
                pk[0] = (_Float16)G[0][i2]; pk[1] = (_Float16)G[1][i2];
                pk[2] = (_Float16)G[2][i2]; pk[3] = (_Float16)G[3][i2];
                *(f16x4*)&xg1t[((((q << 2) + i2) & 7) << 9) + (unit << 2)] = pk;
            }
            __syncthreads();
        }
    }

    // peeled act-L1 for step T-1 (its MFMA ran in the last Phase B)
    {
        float gi = sigm_f(a1[0][0]);
        float gf = sigm_f(a1[1][0]);
        float gg = tanh_f(a1[2][0]);
        float go = sigm_f(a1[3][0]);
        cst1 = gf * cst1 + gi * gg;
        float hh = go * tanh_f(cst1);
        if (l < 16) redbuf[unit] = hh;
    }
    __syncthreads();

    // fused FC on h1(T-1)
    if (t < 64) {
        float p = redbuf[t] * fc_w[t] + redbuf[t + 64] * fc_w[t + 64];
        #pragma unroll
        for (int off = 32; off > 0; off >>= 1) p += __shfl_down(p, off, 64);
        if (t == 0) out[b] = p + fc_b[0];
    }
}

extern "C" void kernel_launch(void* const* d_in, const int* in_sizes, int n_in,
                              void* d_out, int out_size, void* d_ws, size_t ws_size,
                              hipStream_t stream) {
    const float* x     = (const float*)d_in[0];
    const float* w_ih0 = (const float*)d_in[1];
    const float* w_hh0 = (const float*)d_in[2];
    const float* b_ih0 = (const float*)d_in[3];
    const float* b_hh0 = (const float*)d_in[4];
    const float* w_ih1 = (const float*)d_in[5];
    const float* w_hh1 = (const float*)d_in[6];
    const float* b_ih1 = (const float*)d_in[7];
    const float* b_hh1 = (const float*)d_in[8];
    const float* fc_w  = (const float*)d_in[9];
    const float* fc_b  = (const float*)d_in[10];
    float* out = (float*)d_out;

    // ws layout: xg [134217728] + 64KB prefetch slack + w0_16 [65536]
    char* ws = (char*)d_ws;
    _Float16* xg    = (_Float16*)(ws);
    _Float16* w0_16 = (_Float16*)(ws + 134217728 + 65536);

    cvt_f32_f16<<<dim3(32), dim3(256), 0, stream>>>(w_ih0, w0_16, (512 * 64) / 4);

    gemm_xg0<<<dim3(MM / 64), dim3(256), 0, stream>>>(x, w0_16, b_ih0, b_hh0, xg);

    lstm_fused<<<dim3(256), dim3(512), 0, stream>>>(w_hh0, w_ih1, w_hh1,
                                                    b_ih1, b_hh1, xg,
                                                    fc_w, fc_b, out);
}

// Round 10
// 663.602 us; speedup vs baseline: 1.0099x; 1.0099x over previous
//
#include <hip/hip_runtime.h>
#include <hip/hip_fp16.h>

// LSTM B=256,T=512,IN=64,H=128,L=2 + FC.
//  K0 cvt  : w_ih0 -> fp16 (tiny)
//  KG      : xg0 = x(f32).Wih0^T + bias -> [B*T][unit][4g] f16 (fused cvt)
//  KF      : phase-staggered recurrences + chunked xg1 GEMM + FC
//
// R10: R9's stagger was issue-serialized: in-order wave issue + compiler
// clustering meant the act-VALU never issued during the MFMA cluster's
// pipe stalls (MfmaUtil 44 + VALUBusy 41 = 85%, busy-times SUM). Fix:
//  (1) source-interleave the (independent) staggered act in 4 slices
//      between the 4 kt MFMA groups + sched_group_barrier ladder
//      {DS_READ, VALU 8, (MFMA 4, VALU 8)x4} pinning the interleave (T19).
//  (2) raw barriers (s_waitcnt lgkmcnt(0) + s_barrier, m201 pattern) in
//      the main loop: __syncthreads' implicit vmcnt(0) drain was stalling
//      every step on the in-flight xg prefetch; now loads span barriers
//      with compiler-counted vmcnt at the consumption point.
// Else identical to R9: Phase A = MFMA-L0(s) || act-L1(prev) -> h1, bar;
// Phase B = MFMA-L1 || act-L0(s) -> h0, bar; CH=8 chunked xg-phase; k=0
// zero-dynamics; k=NCH bounded-garbage tail; stale-acc trick; peeled
// act-L1 epilogue + fused FC.

#define TT 512
#define CH 8
#define NCH 64            // TT / CH
#define MM (256 * 512)
#define HP 136            // padded h0tile row stride

typedef _Float16 f16x4 __attribute__((ext_vector_type(4)));
typedef _Float16 f16x8 __attribute__((ext_vector_type(8)));
typedef float f32x4 __attribute__((ext_vector_type(4)));

#define SGB(m, n) __builtin_amdgcn_sched_group_barrier((m), (n), 0)

__device__ __forceinline__ void bar_lgkm() {
    asm volatile("s_waitcnt lgkmcnt(0)" ::: "memory");
    __builtin_amdgcn_s_barrier();
}

__device__ __forceinline__ float tanh_f(float x) {
    float e = __expf(2.0f * x);
    return 1.0f - 2.0f * __builtin_amdgcn_rcpf(e + 1.0f);
}
__device__ __forceinline__ float sigm_f(float x) {
    return __builtin_amdgcn_rcpf(1.0f + __expf(-x));
}
__device__ __forceinline__ f16x8 cvt8(float4 a, float4 b) {
    f16x8 f;
    f[0] = (_Float16)a.x; f[1] = (_Float16)a.y;
    f[2] = (_Float16)a.z; f[3] = (_Float16)a.w;
    f[4] = (_Float16)b.x; f[5] = (_Float16)b.y;
    f[6] = (_Float16)b.z; f[7] = (_Float16)b.w;
    return f;
}

// ---------------- K0: fp32 -> fp16 cvt (vector4) ----------------
__global__ void cvt_f32_f16(const float* __restrict__ src,
                            _Float16* __restrict__ dst, int n4) {
    int i = blockIdx.x * blockDim.x + threadIdx.x;
    int stride = gridDim.x * blockDim.x;
    for (; i < n4; i += stride) {
        float4 v = ((const float4*)src)[i];
        f16x4 a;
        a[0] = (_Float16)v.x; a[1] = (_Float16)v.y;
        a[2] = (_Float16)v.z; a[3] = (_Float16)v.w;
        ((f16x4*)dst)[i] = a;
    }
}

// ------- KG: xg[M][u][4g] = A32[M,64] . W[512,64]^T + (bih+bhh) ----------
__global__ __launch_bounds__(256, 1) void gemm_xg0(
    const float* __restrict__ A32, const _Float16* __restrict__ W,
    const float* __restrict__ bih, const float* __restrict__ bhh,
    _Float16* __restrict__ out)
{
    const int l  = threadIdx.x & 63;
    const int w  = threadIdx.x >> 6;
    const int mb = blockIdx.x * 64 + w * 16;
    const int c  = l & 15;
    const int q  = l >> 4;

    __shared__ float biasl[512];
    for (int i = threadIdx.x; i < 512; i += 256) biasl[i] = bih[i] + bhh[i];
    __syncthreads();

    f32x4 C[32];
    #pragma unroll
    for (int i = 0; i < 32; ++i) C[i] = (f32x4){0.f, 0.f, 0.f, 0.f};

    #pragma unroll
    for (int ks = 0; ks < 2; ++ks) {
        const float* ap = A32 + (size_t)(mb + c) * 64 + ks * 32 + q * 8;
        f16x8 Af = cvt8(((const float4*)ap)[0], ((const float4*)ap)[1]);
        #pragma unroll
        for (int nt = 0; nt < 32; ++nt) {
            f16x8 Bf = *(const f16x8*)(W + (size_t)(nt * 16 + c) * 64 + ks * 32 + q * 8);
            C[nt] = __builtin_amdgcn_mfma_f32_16x16x32_f16(Af, Bf, C[nt], 0, 0, 0);
        }
    }
    #pragma unroll
    for (int uu = 0; uu < 8; ++uu) {
        float b0 = biasl[uu * 16 + c];
        float b1 = biasl[128 + uu * 16 + c];
        float b2 = biasl[256 + uu * 16 + c];
        float b3 = biasl[384 + uu * 16 + c];
        #pragma unroll
        for (int i = 0; i < 4; ++i) {
            int row = mb + q * 4 + i;
            f16x4 pk;
            pk[0] = (_Float16)(C[uu][i]      + b0);
            pk[1] = (_Float16)(C[8 + uu][i]  + b1);
            pk[2] = (_Float16)(C[16 + uu][i] + b2);
            pk[3] = (_Float16)(C[24 + uu][i] + b3);
            ((f16x4*)out)[(size_t)row * 128 + uu * 16 + c] = pk;
        }
    }
}

// ---------------- KF: phase-staggered, issue-interleaved ----------------
__global__
__attribute__((amdgpu_flat_work_group_size(512, 512), amdgpu_waves_per_eu(2, 2)))
void lstm_fused(
    const float* __restrict__ whh0, const float* __restrict__ wih1,
    const float* __restrict__ whh1,
    const float* __restrict__ bih1, const float* __restrict__ bhh1,
    const _Float16* __restrict__ xg0,   // [B*T][unit][4g] fp16 (bias incl.)
    const float* __restrict__ fc_w, const float* __restrict__ fc_b,
    float* __restrict__ out)
{
    const int t = threadIdx.x;
    const int b = blockIdx.x;
    const int w = t >> 6;
    const int l = t & 63;
    const int q = l >> 4;            // quad 0..3
    const int c = l & 15;
    const int unit = (w << 4) + c;   // 0..127

    __shared__ __align__(16) _Float16 w1lds[512 * 128];   // 128 KB
    __shared__ __align__(16) _Float16 xg1t[CH * 512];     //   8 KB
    __shared__ __align__(16) _Float16 h0tile[CH * HP];    // 2176 B
    __shared__ __align__(16) _Float16 h1buf[128];         //  256 B
    __shared__ float redbuf[128];                         //  512 B

    // ---- stage Wih1 -> LDS (one row/thread, cvt + chunk-XOR swizzle) ----
    {
        const int r = t;
        const float* src = wih1 + (size_t)r * 128;
        #pragma unroll
        for (int j = 0; j < 16; ++j)
            *(f16x8*)&w1lds[r * 128 + ((j ^ (r & 7)) << 3)] =
                cvt8(((const float4*)src)[2 * j], ((const float4*)src)[2 * j + 1]);
    }

    // ---- resident B-frags: Whh0/Whh1 rows g*128+unit, k = kt*32+q*8 ----
    f16x8 B0[4][4], B1[4][4];
    #pragma unroll
    for (int g = 0; g < 4; ++g) {
        #pragma unroll
        for (int kt = 0; kt < 4; ++kt) {
            const size_t off = (size_t)((g << 7) + unit) * 128 + (kt << 5) + (q << 3);
            B0[g][kt] = cvt8(((const float4*)(whh0 + off))[0],
                             ((const float4*)(whh0 + off))[1]);
            B1[g][kt] = cvt8(((const float4*)(whh1 + off))[0],
                             ((const float4*)(whh1 + off))[1]);
        }
    }
    float bias1g[4];
    #pragma unroll
    for (int g = 0; g < 4; ++g)
        bias1g[g] = bih1[(g << 7) + unit] + bhh1[(g << 7) + unit];

    // zeros: xg1t (k=0 L1 zero-dynamics), h1buf, h0 ring slot CH-1.
    {
        int i = t;                                   // CH*512/8 = 512 f4 slots
        ((float4*)xg1t)[i] = make_float4(0.f, 0.f, 0.f, 0.f);
    }
    if (t < 128) {
        h1buf[t] = (_Float16)0.f;
        h0tile[(CH - 1) * HP + t] = (_Float16)0.f;
    }

    // xg0 rotating prefetch regs (depth 2, compile-time indexed).
    const f16x4* __restrict__ xgp = (const f16x4*)xg0 + (size_t)b * TT * 128 + unit;
    f16x4 xr[4];
    xr[0] = xgp[0];
    xr[1] = xgp[128];
    xr[2] = xr[0]; xr[3] = xr[0];   // overwritten before first use

    // persistent accumulators; only [0] ever read (stale-lane trick).
    f32x4 a0[4], a1[4];
    #pragma unroll
    for (int g = 0; g < 4; ++g) {
        a0[g] = (f32x4){0.f, 0.f, 0.f, 0.f};
        a1[g] = (f32x4){0.f, 0.f, 0.f, 0.f};
    }
    float cst0 = 0.f, cst1 = 0.f;
    __syncthreads();

    #pragma unroll 1
    for (int k = 0; k <= NCH; ++k) {
        #pragma unroll
        for (int j = 0; j < CH; ++j) {
            const int rp = (j + CH - 1) & (CH - 1);

            // ================= Phase A =================
            // MFMA-L0(s) [reads h0(s-1)] interleaved with act-L1(prev).
            f16x4 xv = xr[j & 3];
            xr[(j + 2) & 3] = xgp[(size_t)(k * CH + j + 2) * 128];  // spans bars
            #pragma unroll
            for (int g = 0; g < 4; ++g) a0[g][0] = (float)xv[g];

            f16x8 Af0[4];
            #pragma unroll
            for (int kt = 0; kt < 4; ++kt)
                Af0[kt] = *(const f16x8*)&h0tile[rp * HP + (kt << 5) + (q << 3)];

            #pragma unroll
            for (int g = 0; g < 4; ++g)
                a0[g] = __builtin_amdgcn_mfma_f32_16x16x32_f16(Af0[0], B0[g][0], a0[g], 0, 0, 0);
            float gi1 = sigm_f(a1[0][0]);            // act-L1 slice 0
            float gf1 = sigm_f(a1[1][0]);
            #pragma unroll
            for (int g = 0; g < 4; ++g)
                a0[g] = __builtin_amdgcn_mfma_f32_16x16x32_f16(Af0[1], B0[g][1], a0[g], 0, 0, 0);
            float gg1 = tanh_f(a1[2][0]);            // act-L1 slice 1
            float go1 = sigm_f(a1[3][0]);
            #pragma unroll
            for (int g = 0; g < 4; ++g)
                a0[g] = __builtin_amdgcn_mfma_f32_16x16x32_f16(Af0[2], B0[g][2], a0[g], 0, 0, 0);
            cst1 = gf1 * cst1 + gi1 * gg1;           // act-L1 slice 2
            float th1 = tanh_f(cst1);
            #pragma unroll
            for (int g = 0; g < 4; ++g)
                a0[g] = __builtin_amdgcn_mfma_f32_16x16x32_f16(Af0[3], B0[g][3], a0[g], 0, 0, 0);
            {                                        // act-L1 slice 3
                float hh1 = go1 * th1;
                if (l < 16) h1buf[unit] = (_Float16)hh1;
            }
            // pin the interleave: reads first, VALU warms read-latency,
            // then alternate {MFMA 4, VALU 8}.
            SGB(0x100, 4); SGB(0x2, 8);
            SGB(0x8, 4);   SGB(0x2, 8);
            SGB(0x8, 4);   SGB(0x2, 8);
            SGB(0x8, 4);   SGB(0x2, 8);
            SGB(0x8, 4);
            bar_lgkm();   // h1 visible; vm loads stay in flight

            // ================= Phase B =================
            // MFMA-L1 [reads just-written h1] interleaved with act-L0(s).
            f16x4 x1v = *(const f16x4*)&xg1t[(j << 9) + (unit << 2)];
            #pragma unroll
            for (int g = 0; g < 4; ++g) a1[g][0] = (float)x1v[g];

            f16x8 Af1[4];
            #pragma unroll
            for (int kt = 0; kt < 4; ++kt)
                Af1[kt] = *(const f16x8*)&h1buf[(kt << 5) + (q << 3)];

            #pragma unroll
            for (int g = 0; g < 4; ++g)
                a1[g] = __builtin_amdgcn_mfma_f32_16x16x32_f16(Af1[0], B1[g][0], a1[g], 0, 0, 0);
            float gi0 = sigm_f(a0[0][0]);            // act-L0 slice 0
            float gf0 = sigm_f(a0[1][0]);
            #pragma unroll
            for (int g = 0; g < 4; ++g)
                a1[g] = __builtin_amdgcn_mfma_f32_16x16x32_f16(Af1[1], B1[g][1], a1[g], 0, 0, 0);
            float gg0 = tanh_f(a0[2][0]);            // act-L0 slice 1
            float go0 = sigm_f(a0[3][0]);
            #pragma unroll
            for (int g = 0; g < 4; ++g)
                a1[g] = __builtin_amdgcn_mfma_f32_16x16x32_f16(Af1[2], B1[g][2], a1[g], 0, 0, 0);
            cst0 = gf0 * cst0 + gi0 * gg0;           // act-L0 slice 2
            float th0 = tanh_f(cst0);
            #pragma unroll
            for (int g = 0; g < 4; ++g)
                a1[g] = __builtin_amdgcn_mfma_f32_16x16x32_f16(Af1[3], B1[g][3], a1[g], 0, 0, 0);
            {                                        // act-L0 slice 3
                float hh0 = go0 * th0;
                if (l < 16) h0tile[j * HP + unit] = (_Float16)hh0;
            }
            SGB(0x100, 5); SGB(0x2, 8);
            SGB(0x8, 4);   SGB(0x2, 8);
            SGB(0x8, 4);   SGB(0x2, 8);
            SGB(0x8, 4);   SGB(0x2, 8);
            SGB(0x8, 4);
            bar_lgkm();   // h0 visible
        }

        // ---- xg-phase: xg1t = h0tile(chunk k) @ Wih1^T + b1 ----
        if (k < NCH) {
            f32x4 G[4];
            #pragma unroll
            for (int g = 0; g < 4; ++g)
                G[g] = (f32x4){bias1g[g], bias1g[g], bias1g[g], bias1g[g]};
            #pragma unroll
            for (int kt = 0; kt < 4; ++kt) {
                f16x8 Ah = *(const f16x8*)&h0tile[(c & 7) * HP + (kt << 5) + (q << 3)];
                #pragma unroll
                for (int g = 0; g < 4; ++g) {
                    f16x8 Bg = *(const f16x8*)&w1lds[(((g << 7) + unit) << 7) +
                                   ((((kt << 2) + q) ^ (c & 7)) << 3)];
                    G[g] = __builtin_amdgcn_mfma_f32_16x16x32_f16(Ah, Bg, G[g], 0, 0, 0);
                }
            }
            #pragma unroll
            for (int i2 = 0; i2 < 4; ++i2) {   // D rows 8..15 dup rows 0..7
                f16x4 pk;
                pk[0] = (_Float16)G[0][i2]; pk[1] = (_Float16)G[1][i2];
                pk[2] = (_Float16)G[2][i2]; pk[3] = (_Float16)G[3][i2];
                *(f16x4*)&xg1t[((((q << 2) + i2) & 7) << 9) + (unit << 2)] = pk;
            }
            bar_lgkm();
        }
    }

    // peeled act-L1 for step T-1 (its MFMA ran in the last Phase B)
    {
        float gi = sigm_f(a1[0][0]);
        float gf = sigm_f(a1[1][0]);
        float gg = tanh_f(a1[2][0]);
        float go = sigm_f(a1[3][0]);
        cst1 = gf * cst1 + gi * gg;
        float hh = go * tanh_f(cst1);
        if (l < 16) redbuf[unit] = hh;
    }
    __syncthreads();

    // fused FC on h1(T-1)
    if (t < 64) {
        float p = redbuf[t] * fc_w[t] + redbuf[t + 64] * fc_w[t + 64];
        #pragma unroll
        for (int off = 32; off > 0; off >>= 1) p += __shfl_down(p, off, 64);
        if (t == 0) out[b] = p + fc_b[0];
    }
}

extern "C" void kernel_launch(void* const* d_in, const int* in_sizes, int n_in,
                              void* d_out, int out_size, void* d_ws, size_t ws_size,
                              hipStream_t stream) {
    const float* x     = (const float*)d_in[0];
    const float* w_ih0 = (const float*)d_in[1];
    const float* w_hh0 = (const float*)d_in[2];
    const float* b_ih0 = (const float*)d_in[3];
    const float* b_hh0 = (const float*)d_in[4];
    const float* w_ih1 = (const float*)d_in[5];
    const float* w_hh1 = (const float*)d_in[6];
    const float* b_ih1 = (const float*)d_in[7];
    const float* b_hh1 = (const float*)d_in[8];
    const float* fc_w  = (const float*)d_in[9];
    const float* fc_b  = (const float*)d_in[10];
    float* out = (float*)d_out;

    // ws layout: xg [134217728] + 64KB prefetch slack + w0_16 [65536]
    char* ws = (char*)d_ws;
    _Float16* xg    = (_Float16*)(ws);
    _Float16* w0_16 = (_Float16*)(ws + 134217728 + 65536);

    cvt_f32_f16<<<dim3(32), dim3(256), 0, stream>>>(w_ih0, w0_16, (512 * 64) / 4);

    gemm_xg0<<<dim3(MM / 64), dim3(256), 0, stream>>>(x, w0_16, b_ih0, b_hh0, xg);

    lstm_fused<<<dim3(256), dim3(512), 0, stream>>>(w_hh0, w_ih1, w_hh1,
                                                    b_ih1, b_hh1, xg,
                                                    fc_w, fc_b, out);
}